// Round 4
// baseline (924.472 us; speedup 1.0000x reference)
//
#include <hip/hip_runtime.h>

// ---------------------------------------------------------------------------
// SpatialTransformer, single-dispatch mega-kernel (r12).
// r11 post-mortem: hipLaunchCooperativeKernel silently failed in this harness
// (absmax == max|ref| -> output stayed zero; launch never ran). Same fusion,
// but grid-wide sync is now a SOFTWARE barrier (sense-reversing counter+gen in
// ws, device-scope __hip_atomic_* + __threadfence, s_sleep poll). Coresidency
// is guaranteed by resource math: 512 blocks, __launch_bounds__(256,2) caps
// VGPR<=256 (>=2 blocks/CU), LDS 18432B (8/CU) -> 256 CUs x 2 = 512 resident.
// Barrier region zeroed via hipMemsetAsync on stream (capture-safe).
// Phase bodies are the verified r10 kernels, index-remapped to 512x256.
// ---------------------------------------------------------------------------

#define NEG_SLOPE 0.1f
#define BN_EPS 1e-3f
#define NBLOCKS 512u

typedef float vfloat4 __attribute__((ext_vector_type(4)));

__device__ __forceinline__ void fma4v(float pv, float4 wq, float* __restrict__ acc) {
    acc[0] = fmaf(pv, wq.x, acc[0]);
    acc[1] = fmaf(pv, wq.y, acc[1]);
    acc[2] = fmaf(pv, wq.z, acc[2]);
    acc[3] = fmaf(pv, wq.w, acc[3]);
}

// Sense-reversing grid barrier. counter/gen live in ws (zeroed by memsetAsync
// before launch). Last arriver resets counter (relaxed) then flips gen
// (release); waiters spin on gen (acquire). Agent scope => L2 wb/inv across
// XCDs per the LLVM memory model. Leaves counter==0 for the next use.
__device__ __forceinline__ void grid_barrier(unsigned* counter, unsigned* gen) {
    __syncthreads();
    if (threadIdx.x == 0) {
        __threadfence();
        unsigned g = __hip_atomic_load(gen, __ATOMIC_RELAXED, __HIP_MEMORY_SCOPE_AGENT);
        unsigned arrived = __hip_atomic_fetch_add(counter, 1u, __ATOMIC_ACQ_REL,
                                                  __HIP_MEMORY_SCOPE_AGENT);
        if (arrived == NBLOCKS - 1u) {
            __hip_atomic_store(counter, 0u, __ATOMIC_RELAXED, __HIP_MEMORY_SCOPE_AGENT);
            __hip_atomic_store(gen, g + 1u, __ATOMIC_RELEASE, __HIP_MEMORY_SCOPE_AGENT);
        } else {
            while (__hip_atomic_load(gen, __ATOMIC_ACQUIRE, __HIP_MEMORY_SCOPE_AGENT) == g) {
                __builtin_amdgcn_s_sleep(8);
            }
        }
        __threadfence();
    }
    __syncthreads();
}

__global__ __launch_bounds__(256, 2) void st_mega(
    const float* __restrict__ x,
    const float* __restrict__ c1k, const float* __restrict__ c1b,
    const float* __restrict__ c2k, const float* __restrict__ c2b,
    const float* __restrict__ c3k, const float* __restrict__ c3b,
    const float* __restrict__ gamma, const float* __restrict__ beta,
    const float* __restrict__ mean, const float* __restrict__ var,
    const float* __restrict__ d1k, const float* __restrict__ d1b,
    const float* __restrict__ d2k, const float* __restrict__ d2b,
    const float* __restrict__ d3k, const float* __restrict__ d3b,
    float* __restrict__ Ap, float* __restrict__ Bp,
    float* __restrict__ partial, float* __restrict__ theta,
    unsigned* __restrict__ barC, unsigned* __restrict__ barG,
    float* __restrict__ out)
{
    __shared__ __align__(16) float smem[4608];      // 18432 B union
    const int t = threadIdx.x;
    const int bid = blockIdx.x;
    const int gtid = bid * 256 + t;                 // 0..131071
    const int lane = t & 63;
    float* xip = Ap;                                // conv3 output aliases Ap

    // ================= phase 1: conv1 (1->8) + relu + pool =================
#pragma unroll
    for (int it = 0; it < 2; ++it) {
        int idx = it * 131072 + gtid;               // 262144 pooled px
        int px = idx & 127, py = (idx >> 7) & 127, b = idx >> 14;
        const float* xb = x + b * 65536;
        int iy0 = 2 * py - 1, ix0 = 2 * px - 1;
        float p[16];
#pragma unroll
        for (int r = 0; r < 4; ++r) {
            int iy = iy0 + r;
            bool oky = (iy >= 0) && (iy < 256);
#pragma unroll
            for (int cc = 0; cc < 4; ++cc) {
                int ix = ix0 + cc;
                bool ok = oky && (ix >= 0) && (ix < 256);
                p[r * 4 + cc] = ok ? xb[iy * 256 + ix] : 0.0f;
            }
        }
        float m[8];
#pragma unroll
        for (int co = 0; co < 8; ++co) m[co] = -1e30f;
#pragma unroll
        for (int oy = 0; oy < 2; ++oy)
#pragma unroll
            for (int ox = 0; ox < 2; ++ox) {
                float acc[8];
#pragma unroll
                for (int co = 0; co < 8; ++co) acc[co] = 0.0f;
#pragma unroll
                for (int ky = 0; ky < 3; ++ky)
#pragma unroll
                    for (int kx = 0; kx < 3; ++kx) {
                        float pv = p[(oy + ky) * 4 + (ox + kx)];
                        const float* wr = c1k + (ky * 3 + kx) * 8;
#pragma unroll
                        for (int co = 0; co < 8; ++co)
                            acc[co] = fmaf(pv, wr[co], acc[co]);
                    }
#pragma unroll
                for (int co = 0; co < 8; ++co) m[co] = fmaxf(m[co], acc[co]);
            }
        float4 o0, o1;
        float r0 = m[0] + c1b[0], r1 = m[1] + c1b[1], r2 = m[2] + c1b[2], r3 = m[3] + c1b[3];
        float r4 = m[4] + c1b[4], r5 = m[5] + c1b[5], r6 = m[6] + c1b[6], r7 = m[7] + c1b[7];
        o0.x = r0 > 0.f ? r0 : 0.f; o0.y = r1 > 0.f ? r1 : 0.f;
        o0.z = r2 > 0.f ? r2 : 0.f; o0.w = r3 > 0.f ? r3 : 0.f;
        o1.x = r4 > 0.f ? r4 : 0.f; o1.y = r5 > 0.f ? r5 : 0.f;
        o1.z = r6 > 0.f ? r6 : 0.f; o1.w = r7 > 0.f ? r7 : 0.f;
        float* o = Ap + ((b * 130 + py + 1) * 130 + (px + 1)) * 8;
        *(float4*)o = o0;
        *(float4*)(o + 4) = o1;

        const float4 z4 = {0.f, 0.f, 0.f, 0.f};
        if (idx < 8256) {                           // Ap border
            int bb = idx / 516, tt = idx - bb * 516;
            int iy, ix;
            if (tt < 130)      { iy = 0;        ix = tt; }
            else if (tt < 260) { iy = 129;      ix = tt - 130; }
            else if (tt < 388) { iy = tt - 259; ix = 0; }
            else               { iy = tt - 387; ix = 129; }
            float* d = Ap + ((bb * 130 + iy) * 130 + ix) * 8;
            *(float4*)d = z4; *(float4*)(d + 4) = z4;
        } else if (idx < 12416) {                   // Bp border
            int r = idx - 8256;
            int bb = r / 260, tt = r - bb * 260;
            int iy, ix;
            if (tt < 66)       { iy = 0;        ix = tt; }
            else if (tt < 132) { iy = 65;       ix = tt - 66; }
            else if (tt < 196) { iy = tt - 131; ix = 0; }
            else               { iy = tt - 195; ix = 65; }
            float* d = Bp + ((bb * 66 + iy) * 66 + ix) * 16;
            *(float4*)d = z4; *(float4*)(d + 4) = z4;
            *(float4*)(d + 8) = z4; *(float4*)(d + 12) = z4;
        }
    }
    grid_barrier(barC, barG);

    // ================= phase 2: conv2 (8->16) + relu + pool ================
    {
        for (int i = t; i < 1152; i += 256) smem[i] = c2k[i];
        __syncthreads();
        int wv = __builtin_amdgcn_readfirstlane(t >> 6);   // co-quad 0..3
        int cobase = wv * 4;
#pragma unroll
        for (int it = 0; it < 2; ++it) {
            int pixel = (it * 512 + bid) * 64 + lane;      // 65536 pooled px
            int px = pixel & 63, py = (pixel >> 6) & 63, b = pixel >> 12;
            const float* Ab = Ap + b * 135200;
            int rowbase = (2 * py) * 130 + 2 * px;
            float acc[4][4];
#pragma unroll
            for (int pos = 0; pos < 4; ++pos)
#pragma unroll
                for (int c = 0; c < 4; ++c) acc[pos][c] = 0.0f;
#pragma unroll
            for (int ciq = 0; ciq < 2; ++ciq) {
                float ps[64];
#pragma unroll
                for (int r = 0; r < 4; ++r)
#pragma unroll
                    for (int cc = 0; cc < 4; ++cc) {
                        float4 v = *(const float4*)(Ab + (rowbase + r * 130 + cc) * 8 + ciq * 4);
                        int cell = r * 4 + cc;
                        ps[cell * 4 + 0] = v.x; ps[cell * 4 + 1] = v.y;
                        ps[cell * 4 + 2] = v.z; ps[cell * 4 + 3] = v.w;
                    }
#pragma unroll
                for (int ky = 0; ky < 3; ++ky)
#pragma unroll
                    for (int kx = 0; kx < 3; ++kx) {
                        int tap = ky * 3 + kx;
#pragma unroll
                        for (int comp = 0; comp < 4; ++comp) {
                            float4 wq = *(const float4*)&smem[((tap * 8 + ciq * 4 + comp) << 4) + cobase];
#pragma unroll
                            for (int oy = 0; oy < 2; ++oy)
#pragma unroll
                                for (int ox = 0; ox < 2; ++ox) {
                                    float pv = ps[((oy + ky) * 4 + (ox + kx)) * 4 + comp];
                                    fma4v(pv, wq, acc[oy * 2 + ox]);
                                }
                        }
                    }
            }
            float4 o;
            float* oc = (float*)&o;
#pragma unroll
            for (int c = 0; c < 4; ++c) {
                float m = fmaxf(fmaxf(acc[0][c], acc[1][c]), fmaxf(acc[2][c], acc[3][c]));
                m += c2b[cobase + c];
                oc[c] = m > 0.0f ? m : 0.0f;
            }
            *(float4*)(Bp + ((b * 66 + py + 1) * 66 + (px + 1)) * 16 + cobase) = o;
        }
    }
    grid_barrier(barC, barG);

    // ============ phase 3: conv3 (16->31) + relu + pool -> xip =============
    {
        for (int i = t; i < 4464; i += 256) {
            int tapci = i / 31;
            int co = i - tapci * 31;
            smem[(tapci << 5) + co] = c3k[i];
        }
        __syncthreads();
        int wv = __builtin_amdgcn_readfirstlane(t >> 6);
        int quad = ((bid & 1) << 2) + wv;                  // 0..7, wave-uniform
        int cobase = quad * 4;
        if (cobase > 27) cobase = 27;
        int pixel = (bid >> 1) * 64 + lane;                // 16384 pooled px
        int b = pixel >> 10;
        int cell = pixel & 1023;
        int ppy = cell >> 5, ppx = cell & 31;
        const float* Bb = Bp + b * 69696;
        int rowbase = (2 * ppy) * 66 + 2 * ppx;
        float acc[4][4];
#pragma unroll
        for (int pos = 0; pos < 4; ++pos)
#pragma unroll
            for (int c = 0; c < 4; ++c) acc[pos][c] = 0.0f;
#pragma unroll 2
        for (int ciq = 0; ciq < 4; ++ciq) {
            float ps[64];
#pragma unroll
            for (int r = 0; r < 4; ++r)
#pragma unroll
                for (int cc = 0; cc < 4; ++cc) {
                    float4 v = *(const float4*)(Bb + (rowbase + r * 66 + cc) * 16 + ciq * 4);
                    int cell2 = r * 4 + cc;
                    ps[cell2 * 4 + 0] = v.x; ps[cell2 * 4 + 1] = v.y;
                    ps[cell2 * 4 + 2] = v.z; ps[cell2 * 4 + 3] = v.w;
                }
#pragma unroll
            for (int ky = 0; ky < 3; ++ky)
#pragma unroll
                for (int kx = 0; kx < 3; ++kx) {
                    int tap = ky * 3 + kx;
#pragma unroll
                    for (int comp = 0; comp < 4; ++comp) {
                        float4 wq = *(const float4*)&smem[((tap * 16 + ciq * 4 + comp) << 5) + cobase];
#pragma unroll
                        for (int oy = 0; oy < 2; ++oy)
#pragma unroll
                            for (int ox = 0; ox < 2; ++ox) {
                                float pv = ps[((oy + ky) * 4 + (ox + kx)) * 4 + comp];
                                fma4v(pv, wq, acc[oy * 2 + ox]);
                            }
                    }
                }
        }
        float* xcell = xip + (b << 15) + (cell << 5) + 1 + cobase;  // slot=1+co
#pragma unroll
        for (int c = 0; c < 4; ++c) {
            float m = fmaxf(fmaxf(acc[0][c], acc[1][c]), fmaxf(acc[2][c], acc[3][c]));
            m += c3b[cobase + c];
            xcell[c] = m > 0.0f ? m : 0.0f;
        }
    }
    grid_barrier(barC, barG);

    // ========= phase 4: d1 split-K GEMM with BN fused (blocks 0..495) ======
    if (bid < 496) {
        int s = bid;
        int o = lane;
        int sub = t >> 6;
        int subu = __builtin_amdgcn_readfirstlane(sub);
        int j0 = s * 64 + subu * 16;
        float acc[16];
#pragma unroll
        for (int b = 0; b < 16; ++b) acc[b] = 0.0f;
#pragma unroll 4
        for (int jj = 0; jj < 16; ++jj) {
            int j = j0 + jj;                       // wave-uniform
            float kv = d1k[j * 64 + o];            // coalesced per-lane
            int cell = j / 31;
            int co = j - cell * 31;
            const float* xj = xip + (cell << 5) + 1 + co;
            float sc = gamma[j] * rsqrtf(var[j] + BN_EPS);
            float mn = mean[j], bt = beta[j];
#pragma unroll
            for (int b = 0; b < 16; ++b) {
                float v = xj[b << 15];
                float f = (v - mn) * sc + bt;
                acc[b] = fmaf(f, kv, acc[b]);
            }
        }
        float (*red)[16][64] = (float (*)[16][64])smem;    // 16 KB of union
#pragma unroll
        for (int b = 0; b < 16; ++b) red[sub][b][o] = acc[b];
        __syncthreads();
        if (sub == 0) {
#pragma unroll
            for (int b = 0; b < 16; ++b) {
                float v = red[0][b][o] + red[1][b][o] + red[2][b][o] + red[3][b][o];
                partial[b * 31744 + s * 64 + o] = v;
            }
        }
    }
    grid_barrier(barC, barG);

    // ====== phase 5: head — d1 reduce + relu + d2 + relu + d3 -> theta =====
    if (bid < 16) {
        int b = bid;
        float* redh = smem;                        // [4][64]
        float* h1   = smem + 256;                  // [64]
        float* h2   = smem + 320;                  // [96]
        int o = lane, qq = t >> 6;
        const float* pb = partial + b * 31744;
        float s = 0.0f;
        int sl0 = qq * 124;
#pragma unroll 4
        for (int sl = sl0; sl < sl0 + 124; ++sl)
            s += pb[sl * 64 + o];
        redh[qq * 64 + o] = s;
        __syncthreads();
        if (t < 64) {
            float v = redh[t] + redh[64 + t] + redh[128 + t] + redh[192 + t] + d1b[t];
            h1[t] = v > 0.0f ? v : 0.0f;
        }
        __syncthreads();
        if (t < 96) {
            float v = d2b[t];
            for (int i = 0; i < 64; ++i) v = fmaf(h1[i], d2k[i * 96 + t], v);
            h2[t] = v > 0.0f ? v : 0.0f;
        }
        __syncthreads();
        if (t < 6) {
            float v = d3b[t];
            for (int i = 0; i < 96; ++i) v = fmaf(h2[i], d3k[i * 6 + t], v);
            theta[b * 6 + t] = v;
        }
    }
    grid_barrier(barC, barG);

    // === phase 6: grid-gen + upsample-concat + bilinear sample + lrelu =====
#pragma unroll 1
    for (int it = 0; it < 32; ++it) {
        int id = it * 131072 + gtid;               // 4,194,304 units
        int q = id & 3;
        int pix = id >> 2;
        int ow = pix & 255, oh = (pix >> 8) & 255;
        int b = it >> 1;                           // uniform batch (gtid<2^17)

        const float* th = theta + b * 6;
        float t0 = th[0], t1 = th[1], t2 = th[2], t3 = th[3], t4 = th[4], t5 = th[5];
        float gx = (float)ow * (2.0f / 255.0f) - 1.0f;
        float gy = (float)oh * (2.0f / 255.0f) - 1.0f;
        float sx = gx * t0 + gy * t3 + t2;
        float sy = gx * t1 + gy * t4 + t5;
        float xf = 0.5f * ((sx + 1.0f) * 255.0f);
        float yf = 0.5f * ((sy + 1.0f) * 255.0f);
        float x0 = floorf(xf), y0 = floorf(yf);
        float x1 = x0 + 1.0f, y1 = y0 + 1.0f;
        x0 = fminf(fmaxf(x0, 0.0f), 255.0f);
        x1 = fminf(fmaxf(x1, 0.0f), 255.0f);
        y0 = fminf(fmaxf(y0, 0.0f), 255.0f);
        y1 = fminf(fmaxf(y1, 0.0f), 255.0f);
        float wa = (x1 - xf) * (y1 - yf);
        float wb = (x1 - xf) * (yf - y0);
        float wc = (xf - x0) * (y1 - yf);
        float wd = (xf - x0) * (yf - y0);
        int xi0 = (int)x0, xi1 = (int)x1, yi0 = (int)y0, yi1 = (int)y1;

        const float* cellbase = xip + (b << 15);
        int off = q * 8;
        const float* pa = cellbase + ((((yi0 >> 3) << 5) + (xi0 >> 3)) << 5) + off;
        const float* pbp = cellbase + ((((yi1 >> 3) << 5) + (xi0 >> 3)) << 5) + off;
        const float* pc = cellbase + ((((yi0 >> 3) << 5) + (xi1 >> 3)) << 5) + off;
        const float* pd = cellbase + ((((yi1 >> 3) << 5) + (xi1 >> 3)) << 5) + off;

        float r[8];
#pragma unroll
        for (int k = 0; k < 2; ++k) {
            float4 va = *(const float4*)(pa + 4 * k);
            float4 vb = *(const float4*)(pbp + 4 * k);
            float4 vc = *(const float4*)(pc + 4 * k);
            float4 vd = *(const float4*)(pd + 4 * k);
            r[4 * k]     = fmaf(wa, va.x, fmaf(wb, vb.x, fmaf(wc, vc.x, wd * vd.x)));
            r[4 * k + 1] = fmaf(wa, va.y, fmaf(wb, vb.y, fmaf(wc, vc.y, wd * vd.y)));
            r[4 * k + 2] = fmaf(wa, va.z, fmaf(wb, vb.z, fmaf(wc, vc.z, wd * vd.z)));
            r[4 * k + 3] = fmaf(wa, va.w, fmaf(wb, vb.w, fmaf(wc, vc.w, wd * vd.w)));
        }
        if (q == 0) {
            const float* xb = x + b * 65536;
            float Ia = xb[yi0 * 256 + xi0];
            float Ib = xb[yi1 * 256 + xi0];
            float Ic = xb[yi0 * 256 + xi1];
            float Id = xb[yi1 * 256 + xi1];
            r[0] = fmaf(wa, Ia, fmaf(wb, Ib, fmaf(wc, Ic, wd * Id)));
        }
#pragma unroll
        for (int i = 0; i < 8; ++i) r[i] = r[i] >= 0.0f ? r[i] : NEG_SLOPE * r[i];

        float* ob = out + pix * 32 + off;
        vfloat4 v0 = {r[0], r[1], r[2], r[3]};
        vfloat4 v1 = {r[4], r[5], r[6], r[7]};
        __builtin_nontemporal_store(v0, (vfloat4*)ob);
        __builtin_nontemporal_store(v1, (vfloat4*)(ob + 4));
    }
}

extern "C" void kernel_launch(void* const* d_in, const int* in_sizes, int n_in,
                              void* d_out, int out_size, void* d_ws, size_t ws_size,
                              hipStream_t stream) {
    const float* x     = (const float*)d_in[0];
    const float* c1k   = (const float*)d_in[1];
    const float* c1b   = (const float*)d_in[2];
    const float* c2k   = (const float*)d_in[3];
    const float* c2b   = (const float*)d_in[4];
    const float* c3k   = (const float*)d_in[5];
    const float* c3b   = (const float*)d_in[6];
    const float* gamma = (const float*)d_in[7];
    const float* beta  = (const float*)d_in[8];
    const float* mean  = (const float*)d_in[9];
    const float* var   = (const float*)d_in[10];
    const float* d1k   = (const float*)d_in[11];
    const float* d1b   = (const float*)d_in[12];
    const float* d2k   = (const float*)d_in[13];
    const float* d2b   = (const float*)d_in[14];
    const float* d3k   = (const float*)d_in[15];
    const float* d3b   = (const float*)d_in[16];
    float* out = (float*)d_out;
    float* ws  = (float*)d_ws;

    float* Ap      = ws;                           // 16*130*130*8 = 2163200
    float* Bp      = ws + 2163200;                 // 16*66*66*16 = 1115136
    float* partial = ws + 3278336;                 // 16*31744 = 507904
    float* theta   = ws + 3786240;                 // 96
    unsigned* barC = (unsigned*)(ws + 3786368);    // barrier counter
    unsigned* barG = (unsigned*)(ws + 3786384);    // barrier generation

    // Zero the barrier words (ws is poisoned between runs). Stream-ordered,
    // capture-safe (the harness itself enqueues hipMemsetAsync).
    hipMemsetAsync((void*)barC, 0, 128, stream);

    st_mega<<<NBLOCKS, 256, 0, stream>>>(
        x, c1k, c1b, c2k, c2b, c3k, c3b, gamma, beta, mean, var,
        d1k, d1b, d2k, d2b, d3k, d3b, Ap, Bp, partial, theta,
        barC, barG, out);
}

// Round 5
// 257.470 us; speedup vs baseline: 3.5906x; 3.5906x over previous
//
#include <hip/hip_runtime.h>

// ---------------------------------------------------------------------------
// SpatialTransformer (r13): r10 structure, conv1 FUSED into conv2 via halo
// recompute (no grid-wide dep, no fences). 5 dispatches.
// r12 post-mortem: software grid barriers cost ~150us each on MI355X
// (per-block agent-scope fences -> L2 wbinv storms across 8 XCDs); kernel
// launch boundaries (~12us) are the cheap barrier. So: reduce dispatch count
// only via recompute fusion.
// st_conv12: block = (batch, pooled row py, 4 co-quad waves). Recomputes the
// 4x130x8 conv1 tile it needs into LDS (512 interior px, 2/thread), then the
// verified r10 conv2 body reads LDS instead of global Ap. Ap eliminated.
// conv3/d1/head/sample = r10 verbatim (verified twice).
// ---------------------------------------------------------------------------

#define NEG_SLOPE 0.1f
#define BN_EPS 1e-3f

typedef float vfloat4 __attribute__((ext_vector_type(4)));

__device__ __forceinline__ void fma4v(float pv, float4 wq, float* __restrict__ acc) {
    acc[0] = fmaf(pv, wq.x, acc[0]);
    acc[1] = fmaf(pv, wq.y, acc[1]);
    acc[2] = fmaf(pv, wq.z, acc[2]);
    acc[3] = fmaf(pv, wq.w, acc[3]);
}

// K1: FUSED conv1 (1->8, relu, pool) [recomputed into LDS] + conv2 (8->16,
// relu, pool) -> Bp (padded interior). 1024 blocks x 256 threads.
// Spare side-job: zero Bp borders (idx < 4160), as r10 conv1 did.
__global__ __launch_bounds__(256) void st_conv12(const float* __restrict__ x,
                                                 const float* __restrict__ w1,
                                                 const float* __restrict__ bias1,
                                                 const float* __restrict__ w2,
                                                 const float* __restrict__ bias2,
                                                 float* __restrict__ Bp) {
    __shared__ __align__(16) float at[4160];       // [4][130][8] conv1 tile
    __shared__ __align__(16) float wlds[1152];     // conv2 weights
    int t = threadIdx.x;
    int blk = blockIdx.x;                          // 1024
    int b = blk >> 6, py = blk & 63;

    for (int i = t; i < 1152; i += 256) wlds[i] = w2[i];
    for (int i = t; i < 4160; i += 256) at[i] = 0.0f;
    __syncthreads();

    // ---- conv1 recompute: 4 rows (ar = 2py..2py+3) x 128 interior cols ----
    const float* xb = x + b * 65536;
#pragma unroll
    for (int k = 0; k < 2; ++k) {
        int p = k * 256 + t;                       // 0..511
        int r = p >> 7;                            // tile row 0..3
        int c = (p & 127) + 1;                     // tile col 1..128
        int ar = 2 * py + r;                       // Ap-row 0..129
        if (ar >= 1 && ar <= 128) {
            int pr = ar - 1, pc = c - 1;           // pooled-128 coords
            int iy0 = 2 * pr - 1, ix0 = 2 * pc - 1;
            float pch[16];
#pragma unroll
            for (int rr = 0; rr < 4; ++rr) {
                int iy = iy0 + rr;
                bool oky = (iy >= 0) && (iy < 256);
#pragma unroll
                for (int cc = 0; cc < 4; ++cc) {
                    int ix = ix0 + cc;
                    bool ok = oky && (ix >= 0) && (ix < 256);
                    pch[rr * 4 + cc] = ok ? xb[iy * 256 + ix] : 0.0f;
                }
            }
            float m[8];
#pragma unroll
            for (int co = 0; co < 8; ++co) m[co] = -1e30f;
#pragma unroll
            for (int oy = 0; oy < 2; ++oy)
#pragma unroll
                for (int ox = 0; ox < 2; ++ox) {
                    float acc[8];
#pragma unroll
                    for (int co = 0; co < 8; ++co) acc[co] = 0.0f;
#pragma unroll
                    for (int ky = 0; ky < 3; ++ky)
#pragma unroll
                        for (int kx = 0; kx < 3; ++kx) {
                            float pv = pch[(oy + ky) * 4 + (ox + kx)];
                            const float* wr = w1 + (ky * 3 + kx) * 8;
#pragma unroll
                            for (int co = 0; co < 8; ++co)
                                acc[co] = fmaf(pv, wr[co], acc[co]);
                        }
#pragma unroll
                    for (int co = 0; co < 8; ++co) m[co] = fmaxf(m[co], acc[co]);
                }
            float* dst = &at[(r * 130 + c) * 8];
#pragma unroll
            for (int co = 0; co < 8; ++co) {
                float v = m[co] + bias1[co];
                dst[co] = v > 0.0f ? v : 0.0f;
            }
        }
    }
    __syncthreads();

    // ---- conv2 body (r10 verbatim, ps reads from LDS tile) ----
    int lane = t & 63;
    int wv = __builtin_amdgcn_readfirstlane(t >> 6);   // 0..3 co-quad
    int cobase = wv * 4;
    int px = lane;                                     // pooled col 0..63
    float acc[4][4];
#pragma unroll
    for (int pos = 0; pos < 4; ++pos)
#pragma unroll
        for (int c = 0; c < 4; ++c) acc[pos][c] = 0.0f;

#pragma unroll
    for (int ciq = 0; ciq < 2; ++ciq) {
        float ps[64];                                  // [cell16][comp4]
#pragma unroll
        for (int r = 0; r < 4; ++r)
#pragma unroll
            for (int cc = 0; cc < 4; ++cc) {
                float4 v = *(const float4*)&at[((r * 130) + (2 * px + cc)) * 8 + ciq * 4];
                int cell = r * 4 + cc;
                ps[cell * 4 + 0] = v.x; ps[cell * 4 + 1] = v.y;
                ps[cell * 4 + 2] = v.z; ps[cell * 4 + 3] = v.w;
            }
#pragma unroll
        for (int ky = 0; ky < 3; ++ky)
#pragma unroll
            for (int kx = 0; kx < 3; ++kx) {
                int tap = ky * 3 + kx;
#pragma unroll
                for (int comp = 0; comp < 4; ++comp) {
                    float4 wq = *(const float4*)&wlds[((tap * 8 + ciq * 4 + comp) << 4) + cobase];
#pragma unroll
                    for (int oy = 0; oy < 2; ++oy)
#pragma unroll
                        for (int ox = 0; ox < 2; ++ox) {
                            float pv = ps[((oy + ky) * 4 + (ox + kx)) * 4 + comp];
                            fma4v(pv, wq, acc[oy * 2 + ox]);
                        }
                }
            }
    }
    float4 o;
    float* oc = (float*)&o;
#pragma unroll
    for (int c = 0; c < 4; ++c) {
        float m = fmaxf(fmaxf(acc[0][c], acc[1][c]), fmaxf(acc[2][c], acc[3][c]));
        m += bias2[cobase + c];
        oc[c] = m > 0.0f ? m : 0.0f;
    }
    *(float4*)(Bp + ((b * 66 + py + 1) * 66 + (px + 1)) * 16 + cobase) = o;

    // ---- side-job: zero Bp borders (16 batches x 260 positions) ----
    int idx = blk * 256 + t;
    if (idx < 4160) {
        const float4 z4 = {0.f, 0.f, 0.f, 0.f};
        int bb = idx / 260, tt = idx - bb * 260;
        int iy, ix;
        if (tt < 66)       { iy = 0;        ix = tt; }
        else if (tt < 132) { iy = 65;       ix = tt - 66; }
        else if (tt < 196) { iy = tt - 131; ix = 0; }
        else               { iy = tt - 195; ix = 65; }
        float* d = Bp + ((bb * 66 + iy) * 66 + ix) * 16;
        *(float4*)d = z4; *(float4*)(d + 4) = z4;
        *(float4*)(d + 8) = z4; *(float4*)(d + 12) = z4;
    }
}

// K2: conv3 (16->31) + bias + relu + pool. Bp -> xip. (r10 verbatim)
__global__ __launch_bounds__(256) void st_conv3(const float* __restrict__ Bp,
                                                const float* __restrict__ w,
                                                const float* __restrict__ bias,
                                                float* __restrict__ xip) {
    __shared__ __align__(16) float wlds[9 * 16 * 32];  // stride-32 padded
    int t = threadIdx.x;
    for (int i = t; i < 4464; i += 256) {
        int tapci = i / 31;
        int co = i - tapci * 31;
        wlds[(tapci << 5) + co] = w[i];
    }
    __syncthreads();
    int lane = t & 63;
    int wv = __builtin_amdgcn_readfirstlane(t >> 6);   // 0..3
    int quad = blockIdx.y * 4 + wv;                    // 0..7
    int cobase = quad * 4;
    if (cobase > 27) cobase = 27;
    int pixel = blockIdx.x * 64 + lane;                // 16384 pooled px
    int b = pixel >> 10;
    int cell = pixel & 1023;
    int ppy = cell >> 5, ppx = cell & 31;
    const float* Bb = Bp + b * 69696;                  // 66*66*16
    int rowbase = (2 * ppy) * 66 + 2 * ppx;
    float acc[4][4];
#pragma unroll
    for (int pos = 0; pos < 4; ++pos)
#pragma unroll
        for (int c = 0; c < 4; ++c) acc[pos][c] = 0.0f;

#pragma unroll 2
    for (int ciq = 0; ciq < 4; ++ciq) {
        float ps[64];
#pragma unroll
        for (int r = 0; r < 4; ++r)
#pragma unroll
            for (int cc = 0; cc < 4; ++cc) {
                float4 v = *(const float4*)(Bb + (rowbase + r * 66 + cc) * 16 + ciq * 4);
                int cell2 = r * 4 + cc;
                ps[cell2 * 4 + 0] = v.x; ps[cell2 * 4 + 1] = v.y;
                ps[cell2 * 4 + 2] = v.z; ps[cell2 * 4 + 3] = v.w;
            }
#pragma unroll
        for (int ky = 0; ky < 3; ++ky)
#pragma unroll
            for (int kx = 0; kx < 3; ++kx) {
                int tap = ky * 3 + kx;
#pragma unroll
                for (int comp = 0; comp < 4; ++comp) {
                    float4 wq = *(const float4*)&wlds[((tap * 16 + ciq * 4 + comp) << 5) + cobase];
#pragma unroll
                    for (int oy = 0; oy < 2; ++oy)
#pragma unroll
                        for (int ox = 0; ox < 2; ++ox) {
                            float pv = ps[((oy + ky) * 4 + (ox + kx)) * 4 + comp];
                            fma4v(pv, wq, acc[oy * 2 + ox]);
                        }
                }
            }
    }
    float* xcell = xip + (b << 15) + (cell << 5) + 1 + cobase;  // slot = 1+co
#pragma unroll
    for (int c = 0; c < 4; ++c) {
        float m = fmaxf(fmaxf(acc[0][c], acc[1][c]), fmaxf(acc[2][c], acc[3][c]));
        m += bias[cobase + c];
        xcell[c] = m > 0.0f ? m : 0.0f;
    }
}

// K3: split-K GEMM d1 with BN fused. (r10 verbatim)
__global__ __launch_bounds__(256) void st_d1(const float* __restrict__ xip,
                                             const float* __restrict__ gamma,
                                             const float* __restrict__ beta,
                                             const float* __restrict__ mean,
                                             const float* __restrict__ var,
                                             const float* __restrict__ k1,
                                             float* __restrict__ partial) {
    int t = threadIdx.x, s = blockIdx.x;           // 496 blocks
    int o = t & 63;
    int sub = t >> 6;
    int subu = __builtin_amdgcn_readfirstlane(sub);
    int j0 = s * 64 + subu * 16;
    float acc[16];
#pragma unroll
    for (int b = 0; b < 16; ++b) acc[b] = 0.0f;
#pragma unroll 4
    for (int jj = 0; jj < 16; ++jj) {
        int j = j0 + jj;                           // wave-uniform
        float kv = k1[j * 64 + o];                 // coalesced per-lane
        int cell = j / 31;                         // uniform magic-mul
        int co = j - cell * 31;
        const float* xj = xip + (cell << 5) + 1 + co;
        float sc = gamma[j] * rsqrtf(var[j] + BN_EPS);
        float mn = mean[j], bt = beta[j];
#pragma unroll
        for (int b = 0; b < 16; ++b) {
            float v = xj[b << 15];                 // uniform -> s_load
            float f = (v - mn) * sc + bt;          // BN (same assoc as ref)
            acc[b] = fmaf(f, kv, acc[b]);
        }
    }
    __shared__ float red[4][16][64];
#pragma unroll
    for (int b = 0; b < 16; ++b) red[sub][b][o] = acc[b];
    __syncthreads();
    if (sub == 0) {
#pragma unroll
        for (int b = 0; b < 16; ++b) {
            float v = red[0][b][o] + red[1][b][o] + red[2][b][o] + red[3][b][o];
            partial[b * 31744 + s * 64 + o] = v;   // coalesced
        }
    }
}

// K4: FUSED d1-reduce + bias/relu + d2 (relu) + d3 -> theta. (r10 verbatim)
__global__ __launch_bounds__(256) void st_head(const float* __restrict__ partial,
                                               const float* __restrict__ b1,
                                               const float* __restrict__ k2,
                                               const float* __restrict__ b2,
                                               const float* __restrict__ k3,
                                               const float* __restrict__ b3,
                                               float* __restrict__ theta) {
    int b = blockIdx.x, t = threadIdx.x;
    __shared__ float red[4][64];
    __shared__ float h1[64];
    __shared__ float h2[96];
    int o = t & 63, qq = t >> 6;
    const float* pb = partial + b * 31744;
    float s = 0.0f;
    int sl0 = qq * 124;
#pragma unroll 4
    for (int sl = sl0; sl < sl0 + 124; ++sl)
        s += pb[sl * 64 + o];
    red[qq][o] = s;
    __syncthreads();
    if (t < 64) {
        float v = red[0][t] + red[1][t] + red[2][t] + red[3][t] + b1[t];
        h1[t] = v > 0.0f ? v : 0.0f;
    }
    __syncthreads();
    if (t < 96) {
        float v = b2[t];
        for (int i = 0; i < 64; ++i) v = fmaf(h1[i], k2[i * 96 + t], v);
        h2[t] = v > 0.0f ? v : 0.0f;
    }
    __syncthreads();
    if (t < 6) {
        float v = b3[t];
        for (int i = 0; i < 96; ++i) v = fmaf(h2[i], k3[i * 6 + t], v);
        theta[b * 6 + t] = v;
    }
}

// K5: fused grid-gen + upsample-concat + bilinear sampler + leaky relu.
// (r10 verbatim)
__global__ __launch_bounds__(256) void st_sample(const float* __restrict__ x,
                                                 const float* __restrict__ xip,
                                                 const float* __restrict__ theta,
                                                 float* __restrict__ out) {
    int gid = blockIdx.x * 256 + threadIdx.x;      // 4,194,304
    int q = gid & 3;
    int pix = gid >> 2;                            // 1,048,576 pixels
    int ow = pix & 255, oh = (pix >> 8) & 255;
    int b = __builtin_amdgcn_readfirstlane(blockIdx.x >> 10);

    const float* th = theta + b * 6;
    float t0 = th[0], t1 = th[1], t2 = th[2], t3 = th[3], t4 = th[4], t5 = th[5];
    float gx = (float)ow * (2.0f / 255.0f) - 1.0f;
    float gy = (float)oh * (2.0f / 255.0f) - 1.0f;
    float sx = gx * t0 + gy * t3 + t2;
    float sy = gx * t1 + gy * t4 + t5;
    float xf = 0.5f * ((sx + 1.0f) * 255.0f);
    float yf = 0.5f * ((sy + 1.0f) * 255.0f);
    float x0 = floorf(xf), y0 = floorf(yf);
    float x1 = x0 + 1.0f, y1 = y0 + 1.0f;
    x0 = fminf(fmaxf(x0, 0.0f), 255.0f);
    x1 = fminf(fmaxf(x1, 0.0f), 255.0f);
    y0 = fminf(fmaxf(y0, 0.0f), 255.0f);
    y1 = fminf(fmaxf(y1, 0.0f), 255.0f);
    float wa = (x1 - xf) * (y1 - yf);
    float wb = (x1 - xf) * (yf - y0);
    float wc = (xf - x0) * (y1 - yf);
    float wd = (xf - x0) * (yf - y0);
    int xi0 = (int)x0, xi1 = (int)x1, yi0 = (int)y0, yi1 = (int)y1;

    const float* cellbase = xip + (b << 15);
    int off = q * 8;
    const float* pa = cellbase + ((((yi0 >> 3) << 5) + (xi0 >> 3)) << 5) + off;
    const float* pb = cellbase + ((((yi1 >> 3) << 5) + (xi0 >> 3)) << 5) + off;
    const float* pc = cellbase + ((((yi0 >> 3) << 5) + (xi1 >> 3)) << 5) + off;
    const float* pd = cellbase + ((((yi1 >> 3) << 5) + (xi1 >> 3)) << 5) + off;

    float r[8];
#pragma unroll
    for (int k = 0; k < 2; ++k) {
        float4 va = *(const float4*)(pa + 4 * k);
        float4 vb = *(const float4*)(pb + 4 * k);
        float4 vc = *(const float4*)(pc + 4 * k);
        float4 vd = *(const float4*)(pd + 4 * k);
        r[4 * k]     = fmaf(wa, va.x, fmaf(wb, vb.x, fmaf(wc, vc.x, wd * vd.x)));
        r[4 * k + 1] = fmaf(wa, va.y, fmaf(wb, vb.y, fmaf(wc, vc.y, wd * vd.y)));
        r[4 * k + 2] = fmaf(wa, va.z, fmaf(wb, vb.z, fmaf(wc, vc.z, wd * vd.z)));
        r[4 * k + 3] = fmaf(wa, va.w, fmaf(wb, vb.w, fmaf(wc, vc.w, wd * vd.w)));
    }
    if (q == 0) {
        const float* xb = x + b * 65536;
        float Ia = xb[yi0 * 256 + xi0];
        float Ib = xb[yi1 * 256 + xi0];
        float Ic = xb[yi0 * 256 + xi1];
        float Id = xb[yi1 * 256 + xi1];
        r[0] = fmaf(wa, Ia, fmaf(wb, Ib, fmaf(wc, Ic, wd * Id)));
    }
#pragma unroll
    for (int i = 0; i < 8; ++i) r[i] = r[i] >= 0.0f ? r[i] : NEG_SLOPE * r[i];

    float* ob = out + pix * 32 + off;
    vfloat4 v0 = {r[0], r[1], r[2], r[3]};
    vfloat4 v1 = {r[4], r[5], r[6], r[7]};
    __builtin_nontemporal_store(v0, (vfloat4*)ob);
    __builtin_nontemporal_store(v1, (vfloat4*)(ob + 4));
}

extern "C" void kernel_launch(void* const* d_in, const int* in_sizes, int n_in,
                              void* d_out, int out_size, void* d_ws, size_t ws_size,
                              hipStream_t stream) {
    const float* x     = (const float*)d_in[0];
    const float* c1k   = (const float*)d_in[1];
    const float* c1b   = (const float*)d_in[2];
    const float* c2k   = (const float*)d_in[3];
    const float* c2b   = (const float*)d_in[4];
    const float* c3k   = (const float*)d_in[5];
    const float* c3b   = (const float*)d_in[6];
    const float* gamma = (const float*)d_in[7];
    const float* beta  = (const float*)d_in[8];
    const float* mean  = (const float*)d_in[9];
    const float* var   = (const float*)d_in[10];
    const float* d1k   = (const float*)d_in[11];
    const float* d1b   = (const float*)d_in[12];
    const float* d2k   = (const float*)d_in[13];
    const float* d2b   = (const float*)d_in[14];
    const float* d3k   = (const float*)d_in[15];
    const float* d3b   = (const float*)d_in[16];
    float* out = (float*)d_out;
    float* ws  = (float*)d_ws;

    float* Bp      = ws;                           // 16*66*66*16 = 1115136
    float* xip     = ws + 1115136;                 // 524288
    float* partial = ws + 1639424;                 // 16*31744 = 507904
    float* theta   = ws + 2147328;                 // 96

    st_conv12<<<1024, 256, 0, stream>>>(x, c1k, c1b, c2k, c2b, Bp);
    st_conv3<<<dim3(256, 2), 256, 0, stream>>>(Bp, c3k, c3b, xip);
    st_d1<<<496, 256, 0, stream>>>(xip, gamma, beta, mean, var, d1k, partial);
    st_head<<<16, 256, 0, stream>>>(partial, d1b, d2k, d2b, d3k, d3b, theta);
    st_sample<<<16384, 256, 0, stream>>>(x, xip, theta, out);
}

// Round 6
// 247.589 us; speedup vs baseline: 3.7339x; 1.0399x over previous
//
#include <hip/hip_runtime.h>

// ---------------------------------------------------------------------------
// SpatialTransformer (r14): r13 structure (5 dispatches), st_d1 rebuilt.
// r13 post-mortem: 3rd structural null -> constant ~75us sink present in all
// variants. Located: st_d1's xip reads were wave-uniform SCALAR loads at
// 128KB stride (256 sL1 misses/wave, ~2 waves/SIMD TLP) — identical pattern
// existed in r9's fprime reads, explaining why r10/r13 changes were null.
// Fix: d1 phase A vector-loads + BN-transforms the block's 1024 activations
// into LDS (lane=j coalesced, per-lane magic-div j/31); phase B GEMM reads
// f' via LDS broadcast. Same per-(j,b) arithmetic order -> bit-identical.
// conv12/conv3/head/sample = r13 verbatim (verified).
// ---------------------------------------------------------------------------

#define NEG_SLOPE 0.1f
#define BN_EPS 1e-3f

typedef float vfloat4 __attribute__((ext_vector_type(4)));

__device__ __forceinline__ void fma4v(float pv, float4 wq, float* __restrict__ acc) {
    acc[0] = fmaf(pv, wq.x, acc[0]);
    acc[1] = fmaf(pv, wq.y, acc[1]);
    acc[2] = fmaf(pv, wq.z, acc[2]);
    acc[3] = fmaf(pv, wq.w, acc[3]);
}

// K1: FUSED conv1 (1->8, relu, pool) [recomputed into LDS] + conv2 (8->16,
// relu, pool) -> Bp (padded interior). 1024 blocks x 256 threads.
__global__ __launch_bounds__(256) void st_conv12(const float* __restrict__ x,
                                                 const float* __restrict__ w1,
                                                 const float* __restrict__ bias1,
                                                 const float* __restrict__ w2,
                                                 const float* __restrict__ bias2,
                                                 float* __restrict__ Bp) {
    __shared__ __align__(16) float at[4160];       // [4][130][8] conv1 tile
    __shared__ __align__(16) float wlds[1152];     // conv2 weights
    int t = threadIdx.x;
    int blk = blockIdx.x;                          // 1024
    int b = blk >> 6, py = blk & 63;

    for (int i = t; i < 1152; i += 256) wlds[i] = w2[i];
    for (int i = t; i < 4160; i += 256) at[i] = 0.0f;
    __syncthreads();

    // ---- conv1 recompute: 4 rows (ar = 2py..2py+3) x 128 interior cols ----
    const float* xb = x + b * 65536;
#pragma unroll
    for (int k = 0; k < 2; ++k) {
        int p = k * 256 + t;                       // 0..511
        int r = p >> 7;                            // tile row 0..3
        int c = (p & 127) + 1;                     // tile col 1..128
        int ar = 2 * py + r;                       // Ap-row 0..129
        if (ar >= 1 && ar <= 128) {
            int pr = ar - 1, pc = c - 1;           // pooled-128 coords
            int iy0 = 2 * pr - 1, ix0 = 2 * pc - 1;
            float pch[16];
#pragma unroll
            for (int rr = 0; rr < 4; ++rr) {
                int iy = iy0 + rr;
                bool oky = (iy >= 0) && (iy < 256);
#pragma unroll
                for (int cc = 0; cc < 4; ++cc) {
                    int ix = ix0 + cc;
                    bool ok = oky && (ix >= 0) && (ix < 256);
                    pch[rr * 4 + cc] = ok ? xb[iy * 256 + ix] : 0.0f;
                }
            }
            float m[8];
#pragma unroll
            for (int co = 0; co < 8; ++co) m[co] = -1e30f;
#pragma unroll
            for (int oy = 0; oy < 2; ++oy)
#pragma unroll
                for (int ox = 0; ox < 2; ++ox) {
                    float acc[8];
#pragma unroll
                    for (int co = 0; co < 8; ++co) acc[co] = 0.0f;
#pragma unroll
                    for (int ky = 0; ky < 3; ++ky)
#pragma unroll
                        for (int kx = 0; kx < 3; ++kx) {
                            float pv = pch[(oy + ky) * 4 + (ox + kx)];
                            const float* wr = w1 + (ky * 3 + kx) * 8;
#pragma unroll
                            for (int co = 0; co < 8; ++co)
                                acc[co] = fmaf(pv, wr[co], acc[co]);
                        }
#pragma unroll
                    for (int co = 0; co < 8; ++co) m[co] = fmaxf(m[co], acc[co]);
                }
            float* dst = &at[(r * 130 + c) * 8];
#pragma unroll
            for (int co = 0; co < 8; ++co) {
                float v = m[co] + bias1[co];
                dst[co] = v > 0.0f ? v : 0.0f;
            }
        }
    }
    __syncthreads();

    // ---- conv2 body (r10 verbatim, ps reads from LDS tile) ----
    int lane = t & 63;
    int wv = __builtin_amdgcn_readfirstlane(t >> 6);   // 0..3 co-quad
    int cobase = wv * 4;
    int px = lane;                                     // pooled col 0..63
    float acc[4][4];
#pragma unroll
    for (int pos = 0; pos < 4; ++pos)
#pragma unroll
        for (int c = 0; c < 4; ++c) acc[pos][c] = 0.0f;

#pragma unroll
    for (int ciq = 0; ciq < 2; ++ciq) {
        float ps[64];                                  // [cell16][comp4]
#pragma unroll
        for (int r = 0; r < 4; ++r)
#pragma unroll
            for (int cc = 0; cc < 4; ++cc) {
                float4 v = *(const float4*)&at[((r * 130) + (2 * px + cc)) * 8 + ciq * 4];
                int cell = r * 4 + cc;
                ps[cell * 4 + 0] = v.x; ps[cell * 4 + 1] = v.y;
                ps[cell * 4 + 2] = v.z; ps[cell * 4 + 3] = v.w;
            }
#pragma unroll
        for (int ky = 0; ky < 3; ++ky)
#pragma unroll
            for (int kx = 0; kx < 3; ++kx) {
                int tap = ky * 3 + kx;
#pragma unroll
                for (int comp = 0; comp < 4; ++comp) {
                    float4 wq = *(const float4*)&wlds[((tap * 8 + ciq * 4 + comp) << 4) + cobase];
#pragma unroll
                    for (int oy = 0; oy < 2; ++oy)
#pragma unroll
                        for (int ox = 0; ox < 2; ++ox) {
                            float pv = ps[((oy + ky) * 4 + (ox + kx)) * 4 + comp];
                            fma4v(pv, wq, acc[oy * 2 + ox]);
                        }
                }
            }
    }
    float4 o;
    float* oc = (float*)&o;
#pragma unroll
    for (int c = 0; c < 4; ++c) {
        float m = fmaxf(fmaxf(acc[0][c], acc[1][c]), fmaxf(acc[2][c], acc[3][c]));
        m += bias2[cobase + c];
        oc[c] = m > 0.0f ? m : 0.0f;
    }
    *(float4*)(Bp + ((b * 66 + py + 1) * 66 + (px + 1)) * 16 + cobase) = o;

    // ---- side-job: zero Bp borders (16 batches x 260 positions) ----
    int idx = blk * 256 + t;
    if (idx < 4160) {
        const float4 z4 = {0.f, 0.f, 0.f, 0.f};
        int bb = idx / 260, tt = idx - bb * 260;
        int iy, ix;
        if (tt < 66)       { iy = 0;        ix = tt; }
        else if (tt < 132) { iy = 65;       ix = tt - 66; }
        else if (tt < 196) { iy = tt - 131; ix = 0; }
        else               { iy = tt - 195; ix = 65; }
        float* d = Bp + ((bb * 66 + iy) * 66 + ix) * 16;
        *(float4*)d = z4; *(float4*)(d + 4) = z4;
        *(float4*)(d + 8) = z4; *(float4*)(d + 12) = z4;
    }
}

// K2: conv3 (16->31) + bias + relu + pool. Bp -> xip. (r10 verbatim)
__global__ __launch_bounds__(256) void st_conv3(const float* __restrict__ Bp,
                                                const float* __restrict__ w,
                                                const float* __restrict__ bias,
                                                float* __restrict__ xip) {
    __shared__ __align__(16) float wlds[9 * 16 * 32];  // stride-32 padded
    int t = threadIdx.x;
    for (int i = t; i < 4464; i += 256) {
        int tapci = i / 31;
        int co = i - tapci * 31;
        wlds[(tapci << 5) + co] = w[i];
    }
    __syncthreads();
    int lane = t & 63;
    int wv = __builtin_amdgcn_readfirstlane(t >> 6);   // 0..3
    int quad = blockIdx.y * 4 + wv;                    // 0..7
    int cobase = quad * 4;
    if (cobase > 27) cobase = 27;
    int pixel = blockIdx.x * 64 + lane;                // 16384 pooled px
    int b = pixel >> 10;
    int cell = pixel & 1023;
    int ppy = cell >> 5, ppx = cell & 31;
    const float* Bb = Bp + b * 69696;                  // 66*66*16
    int rowbase = (2 * ppy) * 66 + 2 * ppx;
    float acc[4][4];
#pragma unroll
    for (int pos = 0; pos < 4; ++pos)
#pragma unroll
        for (int c = 0; c < 4; ++c) acc[pos][c] = 0.0f;

#pragma unroll 2
    for (int ciq = 0; ciq < 4; ++ciq) {
        float ps[64];
#pragma unroll
        for (int r = 0; r < 4; ++r)
#pragma unroll
            for (int cc = 0; cc < 4; ++cc) {
                float4 v = *(const float4*)(Bb + (rowbase + r * 66 + cc) * 16 + ciq * 4);
                int cell2 = r * 4 + cc;
                ps[cell2 * 4 + 0] = v.x; ps[cell2 * 4 + 1] = v.y;
                ps[cell2 * 4 + 2] = v.z; ps[cell2 * 4 + 3] = v.w;
            }
#pragma unroll
        for (int ky = 0; ky < 3; ++ky)
#pragma unroll
            for (int kx = 0; kx < 3; ++kx) {
                int tap = ky * 3 + kx;
#pragma unroll
                for (int comp = 0; comp < 4; ++comp) {
                    float4 wq = *(const float4*)&wlds[((tap * 16 + ciq * 4 + comp) << 5) + cobase];
#pragma unroll
                    for (int oy = 0; oy < 2; ++oy)
#pragma unroll
                        for (int ox = 0; ox < 2; ++ox) {
                            float pv = ps[((oy + ky) * 4 + (ox + kx)) * 4 + comp];
                            fma4v(pv, wq, acc[oy * 2 + ox]);
                        }
                }
            }
    }
    float* xcell = xip + (b << 15) + (cell << 5) + 1 + cobase;  // slot = 1+co
#pragma unroll
    for (int c = 0; c < 4; ++c) {
        float m = fmaxf(fmaxf(acc[0][c], acc[1][c]), fmaxf(acc[2][c], acc[3][c]));
        m += bias[cobase + c];
        xcell[c] = m > 0.0f ? m : 0.0f;
    }
}

// K3: split-K GEMM d1 with BN fused (r14 rebuild).
// Phase A: 256 threads vector-load the block's 64 j x 16 b activations from
// xip (lane=j -> coalesced; per-lane magic-div j/31), apply BN (params also
// lane-coalesced), stage f' into LDS [16][64].
// Phase B: GEMM as before; f' read via uniform-address LDS broadcast.
// Same per-(j,b) arithmetic order as r13 -> bit-identical results.
__global__ __launch_bounds__(256) void st_d1(const float* __restrict__ xip,
                                             const float* __restrict__ gamma,
                                             const float* __restrict__ beta,
                                             const float* __restrict__ mean,
                                             const float* __restrict__ var,
                                             const float* __restrict__ k1,
                                             float* __restrict__ partial) {
    __shared__ float flds[16][64];                 // f'[b][j_local], 4KB
    __shared__ float red[4][16][64];               // 16KB
    int t = threadIdx.x, s = blockIdx.x;           // 496 blocks
    int o = t & 63;
    int sub = t >> 6;
    int subu = __builtin_amdgcn_readfirstlane(sub);

    // ---- phase A: load + BN 1024 activations, coalesced ----
    {
        int jl = o;                                // lane = local j
        int j = s * 64 + jl;
        int cell = j / 31;                         // per-lane magic-mul
        int co = j - cell * 31;
        int xoff = (cell << 5) + 1 + co;
        float sc = gamma[j] * rsqrtf(var[j] + BN_EPS);
        float mn = mean[j], bt = beta[j];
#pragma unroll
        for (int p = 0; p < 4; ++p) {
            int b = p * 4 + subu;                  // wave-uniform b
            float v = xip[(b << 15) + xoff];       // coalesced vector load
            flds[b][jl] = (v - mn) * sc + bt;      // same assoc as r13
        }
    }
    __syncthreads();

    // ---- phase B: GEMM (r13 loop, f from LDS broadcast) ----
    int j0l = subu * 16;                           // local j base for this wave
    float acc[16];
#pragma unroll
    for (int b = 0; b < 16; ++b) acc[b] = 0.0f;
#pragma unroll 4
    for (int jj = 0; jj < 16; ++jj) {
        int j = s * 64 + j0l + jj;                 // wave-uniform
        float kv = k1[j * 64 + o];                 // coalesced per-lane
#pragma unroll
        for (int b = 0; b < 16; ++b) {
            float f = flds[b][j0l + jj];           // LDS broadcast
            acc[b] = fmaf(f, kv, acc[b]);
        }
    }
#pragma unroll
    for (int b = 0; b < 16; ++b) red[sub][b][o] = acc[b];
    __syncthreads();
    if (sub == 0) {
#pragma unroll
        for (int b = 0; b < 16; ++b) {
            float v = red[0][b][o] + red[1][b][o] + red[2][b][o] + red[3][b][o];
            partial[b * 31744 + s * 64 + o] = v;   // coalesced
        }
    }
}

// K4: FUSED d1-reduce + bias/relu + d2 (relu) + d3 -> theta. (r10 verbatim)
__global__ __launch_bounds__(256) void st_head(const float* __restrict__ partial,
                                               const float* __restrict__ b1,
                                               const float* __restrict__ k2,
                                               const float* __restrict__ b2,
                                               const float* __restrict__ k3,
                                               const float* __restrict__ b3,
                                               float* __restrict__ theta) {
    int b = blockIdx.x, t = threadIdx.x;
    __shared__ float red[4][64];
    __shared__ float h1[64];
    __shared__ float h2[96];
    int o = t & 63, qq = t >> 6;
    const float* pb = partial + b * 31744;
    float s = 0.0f;
    int sl0 = qq * 124;
#pragma unroll 4
    for (int sl = sl0; sl < sl0 + 124; ++sl)
        s += pb[sl * 64 + o];
    red[qq][o] = s;
    __syncthreads();
    if (t < 64) {
        float v = red[0][t] + red[1][t] + red[2][t] + red[3][t] + b1[t];
        h1[t] = v > 0.0f ? v : 0.0f;
    }
    __syncthreads();
    if (t < 96) {
        float v = b2[t];
        for (int i = 0; i < 64; ++i) v = fmaf(h1[i], k2[i * 96 + t], v);
        h2[t] = v > 0.0f ? v : 0.0f;
    }
    __syncthreads();
    if (t < 6) {
        float v = b3[t];
        for (int i = 0; i < 96; ++i) v = fmaf(h2[i], k3[i * 6 + t], v);
        theta[b * 6 + t] = v;
    }
}

// K5: fused grid-gen + upsample-concat + bilinear sampler + leaky relu.
// (r10 verbatim)
__global__ __launch_bounds__(256) void st_sample(const float* __restrict__ x,
                                                 const float* __restrict__ xip,
                                                 const float* __restrict__ theta,
                                                 float* __restrict__ out) {
    int gid = blockIdx.x * 256 + threadIdx.x;      // 4,194,304
    int q = gid & 3;
    int pix = gid >> 2;                            // 1,048,576 pixels
    int ow = pix & 255, oh = (pix >> 8) & 255;
    int b = __builtin_amdgcn_readfirstlane(blockIdx.x >> 10);

    const float* th = theta + b * 6;
    float t0 = th[0], t1 = th[1], t2 = th[2], t3 = th[3], t4 = th[4], t5 = th[5];
    float gx = (float)ow * (2.0f / 255.0f) - 1.0f;
    float gy = (float)oh * (2.0f / 255.0f) - 1.0f;
    float sx = gx * t0 + gy * t3 + t2;
    float sy = gx * t1 + gy * t4 + t5;
    float xf = 0.5f * ((sx + 1.0f) * 255.0f);
    float yf = 0.5f * ((sy + 1.0f) * 255.0f);
    float x0 = floorf(xf), y0 = floorf(yf);
    float x1 = x0 + 1.0f, y1 = y0 + 1.0f;
    x0 = fminf(fmaxf(x0, 0.0f), 255.0f);
    x1 = fminf(fmaxf(x1, 0.0f), 255.0f);
    y0 = fminf(fmaxf(y0, 0.0f), 255.0f);
    y1 = fminf(fmaxf(y1, 0.0f), 255.0f);
    float wa = (x1 - xf) * (y1 - yf);
    float wb = (x1 - xf) * (yf - y0);
    float wc = (xf - x0) * (y1 - yf);
    float wd = (xf - x0) * (yf - y0);
    int xi0 = (int)x0, xi1 = (int)x1, yi0 = (int)y0, yi1 = (int)y1;

    const float* cellbase = xip + (b << 15);
    int off = q * 8;
    const float* pa = cellbase + ((((yi0 >> 3) << 5) + (xi0 >> 3)) << 5) + off;
    const float* pb = cellbase + ((((yi1 >> 3) << 5) + (xi0 >> 3)) << 5) + off;
    const float* pc = cellbase + ((((yi0 >> 3) << 5) + (xi1 >> 3)) << 5) + off;
    const float* pd = cellbase + ((((yi1 >> 3) << 5) + (xi1 >> 3)) << 5) + off;

    float r[8];
#pragma unroll
    for (int k = 0; k < 2; ++k) {
        float4 va = *(const float4*)(pa + 4 * k);
        float4 vb = *(const float4*)(pb + 4 * k);
        float4 vc = *(const float4*)(pc + 4 * k);
        float4 vd = *(const float4*)(pd + 4 * k);
        r[4 * k]     = fmaf(wa, va.x, fmaf(wb, vb.x, fmaf(wc, vc.x, wd * vd.x)));
        r[4 * k + 1] = fmaf(wa, va.y, fmaf(wb, vb.y, fmaf(wc, vc.y, wd * vd.y)));
        r[4 * k + 2] = fmaf(wa, va.z, fmaf(wb, vb.z, fmaf(wc, vc.z, wd * vd.z)));
        r[4 * k + 3] = fmaf(wa, va.w, fmaf(wb, vb.w, fmaf(wc, vc.w, wd * vd.w)));
    }
    if (q == 0) {
        const float* xb = x + b * 65536;
        float Ia = xb[yi0 * 256 + xi0];
        float Ib = xb[yi1 * 256 + xi0];
        float Ic = xb[yi0 * 256 + xi1];
        float Id = xb[yi1 * 256 + xi1];
        r[0] = fmaf(wa, Ia, fmaf(wb, Ib, fmaf(wc, Ic, wd * Id)));
    }
#pragma unroll
    for (int i = 0; i < 8; ++i) r[i] = r[i] >= 0.0f ? r[i] : NEG_SLOPE * r[i];

    float* ob = out + pix * 32 + off;
    vfloat4 v0 = {r[0], r[1], r[2], r[3]};
    vfloat4 v1 = {r[4], r[5], r[6], r[7]};
    __builtin_nontemporal_store(v0, (vfloat4*)ob);
    __builtin_nontemporal_store(v1, (vfloat4*)(ob + 4));
}

extern "C" void kernel_launch(void* const* d_in, const int* in_sizes, int n_in,
                              void* d_out, int out_size, void* d_ws, size_t ws_size,
                              hipStream_t stream) {
    const float* x     = (const float*)d_in[0];
    const float* c1k   = (const float*)d_in[1];
    const float* c1b   = (const float*)d_in[2];
    const float* c2k   = (const float*)d_in[3];
    const float* c2b   = (const float*)d_in[4];
    const float* c3k   = (const float*)d_in[5];
    const float* c3b   = (const float*)d_in[6];
    const float* gamma = (const float*)d_in[7];
    const float* beta  = (const float*)d_in[8];
    const float* mean  = (const float*)d_in[9];
    const float* var   = (const float*)d_in[10];
    const float* d1k   = (const float*)d_in[11];
    const float* d1b   = (const float*)d_in[12];
    const float* d2k   = (const float*)d_in[13];
    const float* d2b   = (const float*)d_in[14];
    const float* d3k   = (const float*)d_in[15];
    const float* d3b   = (const float*)d_in[16];
    float* out = (float*)d_out;
    float* ws  = (float*)d_ws;

    float* Bp      = ws;                           // 16*66*66*16 = 1115136
    float* xip     = ws + 1115136;                 // 524288
    float* partial = ws + 1639424;                 // 16*31744 = 507904
    float* theta   = ws + 2147328;                 // 96

    st_conv12<<<1024, 256, 0, stream>>>(x, c1k, c1b, c2k, c2b, Bp);
    st_conv3<<<dim3(256, 2), 256, 0, stream>>>(Bp, c3k, c3b, xip);
    st_d1<<<496, 256, 0, stream>>>(xip, gamma, beta, mean, var, d1k, partial);
    st_head<<<16, 256, 0, stream>>>(partial, d1b, d2k, d2b, d3k, d3b, theta);
    st_sample<<<16384, 256, 0, stream>>>(x, xip, theta, out);
}